// Round 8
// baseline (326.907 us; speedup 1.0000x reference)
//
#include <hip/hip_runtime.h>
#include <hip/hip_bf16.h>
#include <cstdint>
#include <cstddef>

// Problem constants (reference: N=8192, C=512, H=8)
#define NN 8192
#define CC 512
#define HH 8

typedef __attribute__((ext_vector_type(8))) short short8;   // 8 bf16 = 4 VGPRs
typedef __attribute__((ext_vector_type(4))) float f32x4;

__device__ __forceinline__ void gload_lds16(const void* g, void* l) {
  __builtin_amdgcn_global_load_lds(
      (const __attribute__((address_space(1))) void*)g,
      (__attribute__((address_space(3))) void*)l, 16, 0, 0);
}

__device__ __forceinline__ f32x4 mfma16(short8 a, short8 b, f32x4 c) {
  return __builtin_amdgcn_mfma_f32_16x16x32_bf16(a, b, c, 0, 0, 0);
}

__device__ __forceinline__ float b2f(unsigned u) {  // low 16 bits = bf16
  union { unsigned i; float f; } x; x.i = u << 16; return x.f;
}

__device__ __forceinline__ void unpack8(uint4 v, float* f) {
  f[0] = b2f(v.x & 0xffffu); f[1] = b2f(v.x >> 16);
  f[2] = b2f(v.y & 0xffffu); f[3] = b2f(v.y >> 16);
  f[4] = b2f(v.z & 0xffffu); f[5] = b2f(v.z >> 16);
  f[6] = b2f(v.w & 0xffffu); f[7] = b2f(v.w >> 16);
}

// ---------------------------------------------------------------------------
// Split-precision projection GEMM: [Q|K] = x @ [W_theta|W_phi] via
// ah*bh + ah*bl + al*bh (Markidis). Output split into bf16 hi+lo pairs
// (= fp32 to 2^-17) for later exact recompute. 128x128 tile, 48 MFMA/barrier.
// ---------------------------------------------------------------------------
__global__ __launch_bounds__(256, 2) void gemm_qk(
    const __hip_bfloat16* __restrict__ ah, const __hip_bfloat16* __restrict__ al, int lda,
    const __hip_bfloat16* __restrict__ bh, const __hip_bfloat16* __restrict__ bl, int ldb,
    int K,
    __hip_bfloat16* __restrict__ outHi, __hip_bfloat16* __restrict__ outLo, int ldc,
    const float* __restrict__ biasCol)
{
  __shared__ __align__(16) char lds[32768];  // Ah | Al | Bh | Bl, 8KB each
  const int tid  = threadIdx.x;
  const int lane = tid & 63;
  const int wave = tid >> 6;
  const int bm = blockIdx.y, bn = blockIdx.x;
  const int wr = wave >> 1, wc = wave & 1;
  const int fr = lane & 15, fq = lane >> 4;

  f32x4 acc[4][4] = {};

  for (int kt = 0; kt < K; kt += 32) {
    __syncthreads();
#pragma unroll
    for (int tile = 0; tile < 4; ++tile) {
      const __hip_bfloat16* tp = (tile == 0) ? ah : (tile == 1) ? al
                               : (tile == 2) ? bh : bl;
      const int ld = (tile < 2) ? lda : ldb;
      const int tb = ((tile < 2) ? bm : bn) * 128;
#pragma unroll
      for (int half = 0; half < 2; ++half) {
        int sub = half * 256 + tid;
        int row = sub >> 2, ch = sub & 3;
        gload_lds16(tp + (size_t)(tb + row) * ld + kt + ch * 8,
                    lds + tile * 8192 + sub * 16);
      }
    }
    __syncthreads();

    short8 fah[4], fal[4], fbh[4], fbl[4];
#pragma unroll
    for (int i = 0; i < 4; ++i) {
      const int ra = (wr * 64 + i * 16 + fr) * 64 + fq * 16;
      const int rb = (wc * 64 + i * 16 + fr) * 64 + fq * 16;
      fah[i] = *(const short8*)(lds +         ra);
      fal[i] = *(const short8*)(lds +  8192 + ra);
      fbh[i] = *(const short8*)(lds + 16384 + rb);
      fbl[i] = *(const short8*)(lds + 24576 + rb);
    }
#pragma unroll
    for (int i = 0; i < 4; ++i)
#pragma unroll
      for (int j = 0; j < 4; ++j) {
        acc[i][j] = mfma16(fah[i], fbh[j], acc[i][j]);
        acc[i][j] = mfma16(fah[i], fbl[j], acc[i][j]);
        acc[i][j] = mfma16(fal[i], fbh[j], acc[i][j]);
      }
  }

  // C/D layout: col = lane&15, row = (lane>>4)*4 + t  [m89]
#pragma unroll
  for (int i = 0; i < 4; ++i)
#pragma unroll
    for (int j = 0; j < 4; ++j) {
      const int rbase = bm * 128 + wr * 64 + i * 16 + fq * 4;
      const int col   = bn * 128 + wc * 64 + j * 16 + fr;
#pragma unroll
      for (int t = 0; t < 4; ++t) {
        float v = acc[i][j][t] + biasCol[col];
        __hip_bfloat16 h = __float2bfloat16(v);
        outHi[(size_t)(rbase + t) * ldc + col] = h;
        outLo[(size_t)(rbase + t) * ldc + col] = __float2bfloat16(v - __bfloat162float(h));
      }
    }
}

// ---------------------------------------------------------------------------
// SIM GEMM — ROUND-19: R17 core (frozen) + T1 XCD-aware block swizzle.
// Theory: three schedules (R14/R16/R17) all plateaued at 33-36% MfmaUtil;
// staged bytes = 512MB / 83.5us = 6.1 TB/s -> staging is L3-bandwidth-bound
// (HBM only 1.1 TB/s; data is L2/L3-resident). Default round-robin d%8 XCD
// assignment scatters same-bm blocks (sharing a 256KB A-panel) across all
// XCDs -> A re-fetched from L3. Swizzle work=(d&7)*128+(d>>3): XCD x's 32
// resident blocks (1/CU) = one full bm-row -> ONE shared A-panel in its L2;
// B-panel L3 re-reads cut ~4x. Bijective (1024%8==0). Output identical
// under any block bijection -> bit-identical numerics.
// ---------------------------------------------------------------------------
__global__ __launch_bounds__(512, 2) void gemm_sim(
    const __hip_bfloat16* __restrict__ A, int lda,
    const __hip_bfloat16* __restrict__ B, int ldb,
    int K,
    float* __restrict__ segMax, unsigned char* __restrict__ sim4)
{
  (void)K;  // fixed: 512 = 16 K-tiles of 32
  __shared__ __align__(16) char lds[98304];  // A: 3x16KB at 0 | B: 3x16KB at 49152
  const int tid  = threadIdx.x;              // 0..511
  const int lane = tid & 63;
  const int wave = tid >> 6;                 // 0..7

  // T1 XCD swizzle: d = dispatch-linear id; XCD(d)=d%8 gets contiguous work chunk.
  const int d    = blockIdx.y * 32 + blockIdx.x;       // grid (32,32)
  const int work = (d & 7) * 128 + (d >> 3);           // bijection on [0,1024)
  const int bm = work >> 5, bn = work & 31;            // work row-major: bm*32+bn

  const int wm = wave >> 2;                  // 0..1  (row half)
  const int wn = wave & 3;                   // 0..3  (col quarter = segment)
  const int fr = lane & 15, fq = lane >> 4;

  // ---- staging source offsets (global pre-swizzle; LDS dest stays linear) --
  int s0 = tid * 16;          s0 ^= ((s0 >> 9) & 1) << 5;
  int s1 = 8192 + tid * 16;   s1 ^= ((s1 >> 9) & 1) << 5;
  const int off0 = (s0 >> 6) * 1024 + ((s0 & 63) >> 1);   // element offset
  const int off1 = (s1 >> 6) * 1024 + ((s1 & 63) >> 1);

  // ---- fragment read bases (swizzled); flip bit is per-thread constant ----
  const int fl = ((fr >> 3) & 1) << 5;
  const int baseAs = (((wm * 128 + fr) * 64) + fq * 16) ^ fl;   // within A buf
  const int baseBs = (((wn * 64 + fr) * 64) + fq * 16) ^ fl;    // within B buf

  const __hip_bfloat16* Ab = A + (size_t)bm * 256 * lda;
  const __hip_bfloat16* Bb = B + (size_t)bn * 256 * ldb;

  // chunk0 = LDS bytes [0,8192) of a tile buf, chunk1 = [8192,16384)
#define STAGE_C0(t, buf) do {                                                \
    const __hip_bfloat16* ap_ = Ab + (t) * 32;                               \
    const __hip_bfloat16* bp_ = Bb + (t) * 32;                               \
    gload_lds16(ap_ + off0, lds + (buf) * 16384 + tid * 16);                 \
    gload_lds16(bp_ + off0, lds + 49152 + (buf) * 16384 + tid * 16);         \
  } while (0)
#define STAGE_C1(t, buf) do {                                                \
    const __hip_bfloat16* ap_ = Ab + (t) * 32;                               \
    const __hip_bfloat16* bp_ = Bb + (t) * 32;                               \
    gload_lds16(ap_ + off1, lds + (buf) * 16384 + 8192 + tid * 16);          \
    gload_lds16(bp_ + off1, lds + 49152 + (buf) * 16384 + 8192 + tid * 16);  \
  } while (0)

  f32x4 acc[8][4] = {};

  // prologue: tiles 0 -> buf0, 1 -> buf1 (FIFO: [t0c0, t0c1, t1c0, t1c1])
  STAGE_C0(0, 0); STAGE_C1(0, 0);
  STAGE_C0(1, 1); STAGE_C1(1, 1);

#pragma unroll
  for (int t = 0; t < 16; ++t) {
    const int buf = t % 3;
    const int nbuf = (t + 2) % 3;
    const char* Abuf = lds + buf * 16384;
    const char* Bbuf = lds + 49152 + buf * 16384;

    // ===== B0: gate tile t for ALL waves =====
    if (t == 15) asm volatile("s_waitcnt vmcnt(0)" ::: "memory");
    else         asm volatile("s_waitcnt vmcnt(4)" ::: "memory");
    __builtin_amdgcn_s_barrier();
    __builtin_amdgcn_sched_barrier(0);

    // ===== interior: compiler-scheduled reads + staging + 32 MFMA =====
    short8 a[8], b4[4];
#pragma unroll
    for (int i = 0; i < 4; ++i)
      a[i] = *(const short8*)(Abuf + baseAs + i * 1024);
#pragma unroll
    for (int j = 0; j < 4; ++j)
      b4[j] = *(const short8*)(Bbuf + baseBs + j * 1024);
    if (t < 14) STAGE_C0(t + 2, nbuf);

#pragma unroll
    for (int i = 0; i < 4; ++i)
#pragma unroll
      for (int j = 0; j < 4; ++j)
        acc[i][j] = mfma16(a[i], b4[j], acc[i][j]);

#pragma unroll
    for (int i = 0; i < 4; ++i)
      a[4 + i] = *(const short8*)(Abuf + baseAs + (4 + i) * 1024);
    if (t < 14) STAGE_C1(t + 2, nbuf);

#pragma unroll
    for (int i = 0; i < 4; ++i)
#pragma unroll
      for (int j = 0; j < 4; ++j)
        acc[4 + i][j] = mfma16(a[4 + i], b4[j], acc[4 + i][j]);
  }
#undef STAGE_C0
#undef STAGE_C1

  // ---- epilogue: segMax + deficit nibbles (same semantics as R12) ----
  const int seg = bn * 4 + wn;
#pragma unroll
  for (int i = 0; i < 8; ++i)
#pragma unroll
    for (int tt = 0; tt < 4; ++tt) {
      const int row = bm * 256 + wm * 128 + i * 16 + fq * 4 + tt;
      float mx = fmaxf(fmaxf(acc[i][0][tt], acc[i][1][tt]),
                       fmaxf(acc[i][2][tt], acc[i][3][tt]));
      mx = fmaxf(mx, __shfl_xor(mx, 1));
      mx = fmaxf(mx, __shfl_xor(mx, 2));
      mx = fmaxf(mx, __shfl_xor(mx, 4));
      mx = fmaxf(mx, __shfl_xor(mx, 8));
      if (fr == 0) segMax[(size_t)row * 128 + seg] = mx;
      unsigned q[4];
#pragma unroll
      for (int j = 0; j < 4; ++j)
        q[j] = (unsigned)fminf((mx - acc[i][j][tt]) * (4.0f / 3.0f), 15.0f);
      unsigned char* dst = sim4 + (size_t)row * (NN / 2) + seg * 32 + fr;
      dst[0]  = (unsigned char)(q[0] | (q[1] << 4));
      dst[16] = (unsigned char)(q[2] | (q[3] << 4));
    }
}

// ---------------------------------------------------------------------------
// Fused select + z-gather, one WAVE per row, barrier-free (R6 lesson).
// ---------------------------------------------------------------------------
__global__ __launch_bounds__(256) void select_zgather(
    const float* __restrict__ segMax, const unsigned char* __restrict__ sim4,
    const __hip_bfloat16* __restrict__ QKhi, const __hip_bfloat16* __restrict__ QKlo,
    const float* __restrict__ x,
    __hip_bfloat16* __restrict__ z)
{
  const int lane = threadIdx.x & 63;
  const int n = blockIdx.x * 4 + (threadIdx.x >> 6);

  float2 sm = ((const float2*)(segMax + (size_t)n * 128))[lane];
  float M = fmaxf(sm.x, sm.y);
#pragma unroll
  for (int off = 32; off; off >>= 1) M = fmaxf(M, __shfl_xor(M, off));

  const unsigned long long b0 = __ballot(sm.x > M - 11.0f);
  const unsigned long long b1 = __ballot(sm.y > M - 11.0f);

  // hoist q row (hi+lo reconstruct, 8 dims/lane)
  float qf[8];
  {
    uint4 qh4 = ((const uint4*)(QKhi + (size_t)n * 1024))[lane];
    uint4 ql4 = ((const uint4*)(QKlo + (size_t)n * 1024))[lane];
    float a[8], b[8];
    unpack8(qh4, a); unpack8(ql4, b);
#pragma unroll
    for (int e = 0; e < 8; ++e) qf[e] = a[e] + b[e];
  }

  const unsigned char* srow4 = sim4 + (size_t)n * (NN / 2);
  const int jj = lane >> 4;            // this lane's col-quarter within a seg
  const int shift = (jj & 1) * 4;
  const int boff = (jj >> 1) * 16 + (lane & 15);

  int nk = 0;
  float se_mine = -1e30f;
  int   mm_mine = 0;
#pragma unroll
  for (int half = 0; half < 2; ++half) {
    unsigned long long mask = half ? b1 : b0;
    while (mask) {
      const int b = __ffsll((unsigned long long)mask) - 1;
      mask &= mask - 1;
      const int seg = 2 * b + half;
      const float segv = __shfl(half ? sm.y : sm.x, b);
      const unsigned byte = srow4[seg * 32 + boff];
      const float sa = segv - 0.75f * (float)((byte >> shift) & 15u);
      unsigned long long cm = __ballot(sa > M - 11.0f);
      while (cm) {
        const int c = __ffsll((unsigned long long)cm) - 1;
        cm &= cm - 1;
        const int m = seg * 64 + c;
        uint4 kh4 = ((const uint4*)(QKhi + (size_t)m * 1024 + 512))[lane];
        uint4 kl4 = ((const uint4*)(QKlo + (size_t)m * 1024 + 512))[lane];
        float a[8], bb[8];
        unpack8(kh4, a); unpack8(kl4, bb);
        float p = 0.f;
#pragma unroll
        for (int e = 0; e < 8; ++e) p += qf[e] * (a[e] + bb[e]);
#pragma unroll
        for (int off = 32; off; off >>= 1) p += __shfl_xor(p, off);
        if (p > M - 10.5f) {
          if (lane == nk) { se_mine = p; mm_mine = m; }
          nk = (nk < 63) ? nk + 1 : nk;
        }
      }
    }
  }

  // exact max + normalizer (selected mass only; tail dropped)
  float Me = (lane < nk) ? se_mine : -1e30f;
#pragma unroll
  for (int off = 32; off; off >>= 1) Me = fmaxf(Me, __shfl_xor(Me, off));
  const float wv = __expf(se_mine - Me);      // valid only for lane < nk
  float Lr = (lane < nk) ? wv : 0.f;
#pragma unroll
  for (int off = 32; off; off >>= 1) Lr += __shfl_xor(Lr, off);

  // gather x rows (fp32, 2KB each, coalesced) into z
  float acc[8] = {};
  for (int i = 0; i < nk; ++i) {
    const int   m = __shfl(mm_mine, i);
    const float w = __shfl(wv, i);
    const float4* row = (const float4*)(x + (size_t)m * CC + 8 * lane);
    float4 a = row[0], b = row[1];
    acc[0] += w * a.x; acc[1] += w * a.y; acc[2] += w * a.z; acc[3] += w * a.w;
    acc[4] += w * b.x; acc[5] += w * b.y; acc[6] += w * b.z; acc[7] += w * b.w;
  }
  const float inv = 1.0f / Lr;
  short8 o;
#pragma unroll
  for (int e = 0; e < 8; ++e) {
    __hip_bfloat16 h = __float2bfloat16(acc[e] * inv);
    o[e] = *(short*)&h;
  }
  *(short8*)(z + (size_t)n * CC + 8 * lane) = o;
}

// ---------------------------------------------------------------------------
// gemm_zwk — R18 (frozen): flat 64-virtual-tile loop, triple-buffered 48KB
// LDS, vmcnt(4)-gated single barrier per vt, XOR swizzle, compiler-scheduled
// interior, per-head relu fold, atomicAdd epilogue.
// ---------------------------------------------------------------------------
__global__ __launch_bounds__(256, 2) void gemm_zwk(
    const __hip_bfloat16* __restrict__ z,
    const __hip_bfloat16* __restrict__ WkT,
    const float* __restrict__ bk,
    float* __restrict__ out)
{
  __shared__ __align__(16) char lds[49152];  // 3 bufs x (z 8KB | B 8KB)
  const int tid  = threadIdx.x;              // 0..255
  const int lane = tid & 63;
  const int wave = tid >> 6;                 // 0..3
  const int bn = blockIdx.x, bm = blockIdx.y, hg = blockIdx.z;
  const int wr = wave >> 1, wc = wave & 1;
  const int fr = lane & 15, fq = lane >> 4;

  // staging: dest chunk bytes d0 = tid*16, d1 = 4096 + tid*16 within an
  // 8KB half-buf (128 rows x 64B); source = dest ^ ((dest>>9)&1)<<5.
  int s0 = tid * 16;         s0 ^= ((s0 >> 9) & 1) << 5;
  int s1 = 4096 + tid * 16;  s1 ^= ((s1 >> 9) & 1) << 5;
  const int r0 = s0 >> 6, c0 = (s0 & 63) >> 1;   // row, K-elem
  const int r1 = s1 >> 6, c1 = (s1 & 63) >> 1;

  // fragment read bases (swizzled); row = {wr|wc}*64 + i*16 + fr -> bit3 = fr bit3
  const int fl = ((fr >> 3) & 1) << 5;
  const int baseA = (((wr * 64 + fr) * 64) + fq * 16) ^ fl;
  const int baseB = (((wc * 64 + fr) * 64) + fq * 16) ^ fl;

  const __hip_bfloat16* zb = z + (size_t)(bm * 128) * CC;

  // vt -> head = hg*4 + (vt>>4), kt = (vt&15)*32
#define STAGE_VT(vt, buf) do {                                               \
    const int h_ = hg * 4 + ((vt) >> 4);                                     \
    const int k_ = ((vt) & 15) * 32;                                         \
    const __hip_bfloat16* Bp_ = WkT + (size_t)(h_ * 512 + bn * 128) * CC;    \
    gload_lds16(zb  + (size_t)r0 * CC + k_ + c0, lds + (buf) * 16384 + tid * 16);        \
    gload_lds16(zb  + (size_t)r1 * CC + k_ + c1, lds + (buf) * 16384 + 4096 + tid * 16); \
    gload_lds16(Bp_ + (size_t)r0 * CC + k_ + c0, lds + (buf) * 16384 + 8192 + tid * 16); \
    gload_lds16(Bp_ + (size_t)r1 * CC + k_ + c1, lds + (buf) * 16384 + 12288 + tid * 16);\
  } while (0)

  f32x4 oacc[4][4] = {};

  // prologue: vt 0 -> buf0, vt 1 -> buf1
  STAGE_VT(0, 0);
  STAGE_VT(1, 1);

#pragma unroll
  for (int hh = 0; hh < 4; ++hh) {
    f32x4 acc[4][4] = {};
#pragma unroll
    for (int k2 = 0; k2 < 16; ++k2) {
      const int vt = hh * 16 + k2;
      const int buf = vt % 3;
      const char* Abuf = lds + buf * 16384;
      const char* Bbuf = lds + buf * 16384 + 8192;

      // gate tile vt for all waves
      if (vt == 63) asm volatile("s_waitcnt vmcnt(0)" ::: "memory");
      else          asm volatile("s_waitcnt vmcnt(4)" ::: "memory");
      __builtin_amdgcn_s_barrier();
      __builtin_amdgcn_sched_barrier(0);

      short8 af[4], bf[4];
#pragma unroll
      for (int i = 0; i < 4; ++i) {
        af[i] = *(const short8*)(Abuf + baseA + i * 1024);
        bf[i] = *(const short8*)(Bbuf + baseB + i * 1024);
      }
      if (vt < 62) STAGE_VT(vt + 2, (vt + 2) % 3);

#pragma unroll
      for (int i = 0; i < 4; ++i)
#pragma unroll
        for (int j = 0; j < 4; ++j)
          acc[i][j] = mfma16(af[i], bf[j], acc[i][j]);
    }

    // per-head relu fold
    const int head = hg * 4 + hh;
#pragma unroll
    for (int j = 0; j < 4; ++j) {
      const int d = bn * 128 + wc * 64 + j * 16 + fr;
      const float bias = bk[head * CC + d];
#pragma unroll
      for (int i = 0; i < 4; ++i)
#pragma unroll
        for (int t = 0; t < 4; ++t)
          oacc[i][j][t] += fmaxf(acc[i][j][t] + bias, 0.f);
    }
  }
#undef STAGE_VT

#pragma unroll
  for (int i = 0; i < 4; ++i)
#pragma unroll
    for (int j = 0; j < 4; ++j) {
      const int rbase = bm * 128 + wr * 64 + i * 16 + fq * 4;
      const int d     = bn * 128 + wc * 64 + j * 16 + fr;
#pragma unroll
      for (int t = 0; t < 4; ++t)
        atomicAdd(out + (size_t)(rbase + t) * CC + d, 0.125f * oacc[i][j][t]);
    }
}

// ---------------------------------------------------------------------------
// Merged prep (one launch, block-aligned ranges):
//   [0, 4194304)          x -> bf16 hi+lo split
//   [4194304, 4718592)    WT[j][c] = (j<512?Wth:Wph)[c][j&511], hi+lo
//   [4718592, 6815744)    WkT[j][c] = W_k[j>>9][c][j&511], bf16
//   [6815744, 6816768)    biasqk
//   [6816768, 7865344)    out zero-init (float4 per thread; atomics target)
// ---------------------------------------------------------------------------
__global__ void prep_all(const float* __restrict__ x,
                         const float* __restrict__ Wth, const float* __restrict__ Wph,
                         const float* __restrict__ bt, const float* __restrict__ bp,
                         const float* __restrict__ Wk,
                         __hip_bfloat16* __restrict__ xhi, __hip_bfloat16* __restrict__ xlo,
                         __hip_bfloat16* __restrict__ wthi, __hip_bfloat16* __restrict__ wtlo,
                         __hip_bfloat16* __restrict__ wkt, float* __restrict__ biasqk,
                         float* __restrict__ outz) {
  int idx = blockIdx.x * 256 + threadIdx.x;
  if (idx < 4194304) {
    float v = x[idx];
    __hip_bfloat16 h = __float2bfloat16(v);
    xhi[idx] = h;
    xlo[idx] = __float2bfloat16(v - __bfloat162float(h));
  } else if (idx < 4718592) {
    int i = idx - 4194304;
    int j = i >> 9, c = i & 511;
    const float* W = (j < 512) ? Wth : Wph;
    float v = W[(size_t)c * 512 + (j & 511)];
    __hip_bfloat16 h = __float2bfloat16(v);
    wthi[i] = h;
    wtlo[i] = __float2bfloat16(v - __bfloat162float(h));
  } else if (idx < 6815744) {
    int i = idx - 4718592;
    int j = i >> 9, c = i & 511;
    float v = Wk[(size_t)(j >> 9) * 262144 + (size_t)c * 512 + (j & 511)];
    wkt[i] = __float2bfloat16(v);
  } else if (idx < 6816768) {
    int i = idx - 6815744;
    biasqk[i] = (i < 512) ? bt[i] : bp[i - 512];
  } else if (idx < 7865344) {
    int i = idx - 6816768;
    ((float4*)outz)[i] = make_float4(0.f, 0.f, 0.f, 0.f);
  }
}

extern "C" void kernel_launch(void* const* d_in, const int* in_sizes, int n_in,
                              void* d_out, int out_size, void* d_ws, size_t ws_size,
                              hipStream_t stream) {
  const float* x  = (const float*)d_in[0];
  const float* Wt = (const float*)d_in[1];
  const float* bt = (const float*)d_in[2];
  const float* Wp = (const float*)d_in[3];
  const float* bp = (const float*)d_in[4];
  const float* Wk = (const float*)d_in[5];
  const float* bk = (const float*)d_in[6];
  float* out = (float*)d_out;

  // ---- workspace layout, peak ~100 MiB ----
  const size_t MB = 1024 * 1024;
  char* w = (char*)d_ws;
  __hip_bfloat16* xhi  = (__hip_bfloat16*)(w + 0 * MB);    // 8 MiB
  __hip_bfloat16* xlo  = (__hip_bfloat16*)(w + 8 * MB);    // 8 MiB
  __hip_bfloat16* WThi = (__hip_bfloat16*)(w + 16 * MB);   // 1 MiB
  __hip_bfloat16* WTlo = (__hip_bfloat16*)(w + 17 * MB);   // 1 MiB
  float*          biasqk = (float*)(w + 18 * MB);          // 4 KiB
  __hip_bfloat16* WkT  = (__hip_bfloat16*)(w + 20 * MB);   // 4 MiB
  __hip_bfloat16* QKhi = (__hip_bfloat16*)(w + 24 * MB);   // 16 MiB
  __hip_bfloat16* QKlo = (__hip_bfloat16*)(w + 40 * MB);   // 16 MiB
  __hip_bfloat16* z    = (__hip_bfloat16*)(w + 56 * MB);   // 8 MiB
  float*          segMax = (float*)(w + 64 * MB);          // 4 MiB
  unsigned char*  sim4   = (unsigned char*)(w + 68 * MB);  // 32 MiB

  // 1. prep + out zero-init (single launch)
  prep_all<<<7865344 / 256, 256, 0, stream>>>(x, Wt, Wp, bt, bp, Wk,
                                              xhi, xlo, WThi, WTlo, WkT, biasqk,
                                              out);

  // 2. [Q|K] projections, split precision, hi+lo outputs (8192 x 1024)
  gemm_qk<<<dim3(1024 / 128, NN / 128), 256, 0, stream>>>(
      xhi, xlo, CC, WThi, WTlo, CC, CC, QKhi, QKlo, 1024, biasqk);

  // 3. Q @ K^T -> segMax + deficit nibbles (256x256, XCD-swizzled)
  gemm_sim<<<dim3(NN / 256, NN / 256), 512, 0, stream>>>(
      QKhi, 1024, QKhi + 512, 1024, CC, segMax, sim4);

  // 4. fused select (nibble-filtered exact recompute) + z-gather
  select_zgather<<<NN / 4, 256, 0, stream>>>(segMax, sim4, QKhi, QKlo, x, z);

  // 5. out[n][d] += 0.125 * sum_{h in hg} relu(z @ W_k[h] + b_k[h])
  gemm_zwk<<<dim3(CC / 128, NN / 128, 2), 256, 0, stream>>>(z, WkT, bk, out);
}

// Round 10
// 313.197 us; speedup vs baseline: 1.0438x; 1.0438x over previous
//
#include <hip/hip_runtime.h>
#include <hip/hip_bf16.h>
#include <cstdint>
#include <cstddef>

// Problem constants (reference: N=8192, C=512, H=8)
#define NN 8192
#define CC 512
#define HH 8

typedef __attribute__((ext_vector_type(8))) short short8;   // 8 bf16 = 4 VGPRs
typedef __attribute__((ext_vector_type(4))) float f32x4;

__device__ __forceinline__ void gload_lds16(const void* g, void* l) {
  __builtin_amdgcn_global_load_lds(
      (const __attribute__((address_space(1))) void*)g,
      (__attribute__((address_space(3))) void*)l, 16, 0, 0);
}

__device__ __forceinline__ f32x4 mfma16(short8 a, short8 b, f32x4 c) {
  return __builtin_amdgcn_mfma_f32_16x16x32_bf16(a, b, c, 0, 0, 0);
}

__device__ __forceinline__ float b2f(unsigned u) {  // low 16 bits = bf16
  union { unsigned i; float f; } x; x.i = u << 16; return x.f;
}

__device__ __forceinline__ void unpack8(uint4 v, float* f) {
  f[0] = b2f(v.x & 0xffffu); f[1] = b2f(v.x >> 16);
  f[2] = b2f(v.y & 0xffffu); f[3] = b2f(v.y >> 16);
  f[4] = b2f(v.z & 0xffffu); f[5] = b2f(v.z >> 16);
  f[6] = b2f(v.w & 0xffffu); f[7] = b2f(v.w >> 16);
}

// ---------------------------------------------------------------------------
// Split-precision projection GEMM: [Q|K] = x @ [W_theta|W_phi] via
// ah*bh + ah*bl + al*bh (Markidis). Output split into bf16 hi+lo pairs
// (= fp32 to 2^-17) for later exact recompute. 128x128 tile, 48 MFMA/barrier.
// ---------------------------------------------------------------------------
__global__ __launch_bounds__(256, 2) void gemm_qk(
    const __hip_bfloat16* __restrict__ ah, const __hip_bfloat16* __restrict__ al, int lda,
    const __hip_bfloat16* __restrict__ bh, const __hip_bfloat16* __restrict__ bl, int ldb,
    int K,
    __hip_bfloat16* __restrict__ outHi, __hip_bfloat16* __restrict__ outLo, int ldc,
    const float* __restrict__ biasCol)
{
  __shared__ __align__(16) char lds[32768];  // Ah | Al | Bh | Bl, 8KB each
  const int tid  = threadIdx.x;
  const int lane = tid & 63;
  const int wave = tid >> 6;
  const int bm = blockIdx.y, bn = blockIdx.x;
  const int wr = wave >> 1, wc = wave & 1;
  const int fr = lane & 15, fq = lane >> 4;

  f32x4 acc[4][4] = {};

  for (int kt = 0; kt < K; kt += 32) {
    __syncthreads();
#pragma unroll
    for (int tile = 0; tile < 4; ++tile) {
      const __hip_bfloat16* tp = (tile == 0) ? ah : (tile == 1) ? al
                               : (tile == 2) ? bh : bl;
      const int ld = (tile < 2) ? lda : ldb;
      const int tb = ((tile < 2) ? bm : bn) * 128;
#pragma unroll
      for (int half = 0; half < 2; ++half) {
        int sub = half * 256 + tid;
        int row = sub >> 2, ch = sub & 3;
        gload_lds16(tp + (size_t)(tb + row) * ld + kt + ch * 8,
                    lds + tile * 8192 + sub * 16);
      }
    }
    __syncthreads();

    short8 fah[4], fal[4], fbh[4], fbl[4];
#pragma unroll
    for (int i = 0; i < 4; ++i) {
      const int ra = (wr * 64 + i * 16 + fr) * 64 + fq * 16;
      const int rb = (wc * 64 + i * 16 + fr) * 64 + fq * 16;
      fah[i] = *(const short8*)(lds +         ra);
      fal[i] = *(const short8*)(lds +  8192 + ra);
      fbh[i] = *(const short8*)(lds + 16384 + rb);
      fbl[i] = *(const short8*)(lds + 24576 + rb);
    }
#pragma unroll
    for (int i = 0; i < 4; ++i)
#pragma unroll
      for (int j = 0; j < 4; ++j) {
        acc[i][j] = mfma16(fah[i], fbh[j], acc[i][j]);
        acc[i][j] = mfma16(fah[i], fbl[j], acc[i][j]);
        acc[i][j] = mfma16(fal[i], fbh[j], acc[i][j]);
      }
  }

  // C/D layout: col = lane&15, row = (lane>>4)*4 + t  [m89]
#pragma unroll
  for (int i = 0; i < 4; ++i)
#pragma unroll
    for (int j = 0; j < 4; ++j) {
      const int rbase = bm * 128 + wr * 64 + i * 16 + fq * 4;
      const int col   = bn * 128 + wc * 64 + j * 16 + fr;
#pragma unroll
      for (int t = 0; t < 4; ++t) {
        float v = acc[i][j][t] + biasCol[col];
        __hip_bfloat16 h = __float2bfloat16(v);
        outHi[(size_t)(rbase + t) * ldc + col] = h;
        outLo[(size_t)(rbase + t) * ldc + col] = __float2bfloat16(v - __bfloat162float(h));
      }
    }
}

// ---------------------------------------------------------------------------
// SIM GEMM — R17 (frozen; R19's XCD swizzle REVERTED: it tripled FETCH_SIZE
// with no time change -> locality remap hurt, and proved the kernel is not
// memory-traffic-bound). vmcnt-gated triple-buffer, compiler-scheduled
// interior, XOR swizzle. 83.5 us, MfmaUtil 36%, bank conflicts 0.
// ---------------------------------------------------------------------------
__global__ __launch_bounds__(512, 2) void gemm_sim(
    const __hip_bfloat16* __restrict__ A, int lda,
    const __hip_bfloat16* __restrict__ B, int ldb,
    int K,
    float* __restrict__ segMax, unsigned char* __restrict__ sim4)
{
  (void)K;  // fixed: 512 = 16 K-tiles of 32
  __shared__ __align__(16) char lds[98304];  // A: 3x16KB at 0 | B: 3x16KB at 49152
  const int tid  = threadIdx.x;              // 0..511
  const int lane = tid & 63;
  const int wave = tid >> 6;                 // 0..7
  const int bm = blockIdx.y, bn = blockIdx.x;
  const int wm = wave >> 2;                  // 0..1  (row half)
  const int wn = wave & 3;                   // 0..3  (col quarter = segment)
  const int fr = lane & 15, fq = lane >> 4;

  // ---- staging source offsets (global pre-swizzle; LDS dest stays linear) --
  int s0 = tid * 16;          s0 ^= ((s0 >> 9) & 1) << 5;
  int s1 = 8192 + tid * 16;   s1 ^= ((s1 >> 9) & 1) << 5;
  const int off0 = (s0 >> 6) * 1024 + ((s0 & 63) >> 1);   // element offset
  const int off1 = (s1 >> 6) * 1024 + ((s1 & 63) >> 1);

  // ---- fragment read bases (swizzled); flip bit is per-thread constant ----
  const int fl = ((fr >> 3) & 1) << 5;
  const int baseAs = (((wm * 128 + fr) * 64) + fq * 16) ^ fl;   // within A buf
  const int baseBs = (((wn * 64 + fr) * 64) + fq * 16) ^ fl;    // within B buf

  const __hip_bfloat16* Ab = A + (size_t)bm * 256 * lda;
  const __hip_bfloat16* Bb = B + (size_t)bn * 256 * ldb;

  // chunk0 = LDS bytes [0,8192) of a tile buf, chunk1 = [8192,16384)
#define STAGE_C0(t, buf) do {                                                \
    const __hip_bfloat16* ap_ = Ab + (t) * 32;                               \
    const __hip_bfloat16* bp_ = Bb + (t) * 32;                               \
    gload_lds16(ap_ + off0, lds + (buf) * 16384 + tid * 16);                 \
    gload_lds16(bp_ + off0, lds + 49152 + (buf) * 16384 + tid * 16);         \
  } while (0)
#define STAGE_C1(t, buf) do {                                                \
    const __hip_bfloat16* ap_ = Ab + (t) * 32;                               \
    const __hip_bfloat16* bp_ = Bb + (t) * 32;                               \
    gload_lds16(ap_ + off1, lds + (buf) * 16384 + 8192 + tid * 16);          \
    gload_lds16(bp_ + off1, lds + 49152 + (buf) * 16384 + 8192 + tid * 16);  \
  } while (0)

  f32x4 acc[8][4] = {};

  // prologue: tiles 0 -> buf0, 1 -> buf1 (FIFO: [t0c0, t0c1, t1c0, t1c1])
  STAGE_C0(0, 0); STAGE_C1(0, 0);
  STAGE_C0(1, 1); STAGE_C1(1, 1);

#pragma unroll
  for (int t = 0; t < 16; ++t) {
    const int buf = t % 3;
    const int nbuf = (t + 2) % 3;
    const char* Abuf = lds + buf * 16384;
    const char* Bbuf = lds + 49152 + buf * 16384;

    // ===== B0: gate tile t for ALL waves =====
    if (t == 15) asm volatile("s_waitcnt vmcnt(0)" ::: "memory");
    else         asm volatile("s_waitcnt vmcnt(4)" ::: "memory");
    __builtin_amdgcn_s_barrier();
    __builtin_amdgcn_sched_barrier(0);

    // ===== interior: compiler-scheduled reads + staging + 32 MFMA =====
    short8 a[8], b4[4];
#pragma unroll
    for (int i = 0; i < 4; ++i)
      a[i] = *(const short8*)(Abuf + baseAs + i * 1024);
#pragma unroll
    for (int j = 0; j < 4; ++j)
      b4[j] = *(const short8*)(Bbuf + baseBs + j * 1024);
    if (t < 14) STAGE_C0(t + 2, nbuf);

#pragma unroll
    for (int i = 0; i < 4; ++i)
#pragma unroll
      for (int j = 0; j < 4; ++j)
        acc[i][j] = mfma16(a[i], b4[j], acc[i][j]);

#pragma unroll
    for (int i = 0; i < 4; ++i)
      a[4 + i] = *(const short8*)(Abuf + baseAs + (4 + i) * 1024);
    if (t < 14) STAGE_C1(t + 2, nbuf);

#pragma unroll
    for (int i = 0; i < 4; ++i)
#pragma unroll
      for (int j = 0; j < 4; ++j)
        acc[4 + i][j] = mfma16(a[4 + i], b4[j], acc[4 + i][j]);
  }
#undef STAGE_C0
#undef STAGE_C1

  // ---- epilogue: segMax + deficit nibbles (same semantics as R12) ----
  const int seg = bn * 4 + wn;
#pragma unroll
  for (int i = 0; i < 8; ++i)
#pragma unroll
    for (int tt = 0; tt < 4; ++tt) {
      const int row = bm * 256 + wm * 128 + i * 16 + fq * 4 + tt;
      float mx = fmaxf(fmaxf(acc[i][0][tt], acc[i][1][tt]),
                       fmaxf(acc[i][2][tt], acc[i][3][tt]));
      mx = fmaxf(mx, __shfl_xor(mx, 1));
      mx = fmaxf(mx, __shfl_xor(mx, 2));
      mx = fmaxf(mx, __shfl_xor(mx, 4));
      mx = fmaxf(mx, __shfl_xor(mx, 8));
      if (fr == 0) segMax[(size_t)row * 128 + seg] = mx;
      unsigned q[4];
#pragma unroll
      for (int j = 0; j < 4; ++j)
        q[j] = (unsigned)fminf((mx - acc[i][j][tt]) * (4.0f / 3.0f), 15.0f);
      unsigned char* dst = sim4 + (size_t)row * (NN / 2) + seg * 32 + fr;
      dst[0]  = (unsigned char)(q[0] | (q[1] << 4));
      dst[16] = (unsigned char)(q[2] | (q[3] << 4));
    }
}

// ---------------------------------------------------------------------------
// Fused select + z-gather — ROUND-20: depth-1 software-pipelined candidate
// and gather loops. The old loops were serial dependent-latency chains:
// candidate i+1's 1KB K-row load only issued after candidate i's full
// {load -> unpack -> dot -> 6-shfl reduce -> branch}. Candidate indices come
// from the (load-free) nibble ballot, so the NEXT candidate's loads are
// issued BEFORE consuming the current one's — counted waitcnt keeps them in
// flight across the compute (~300cy latency hidden under ~80cy compute,
// pipelined). Same for the x-row gather (indices from registers via shfl).
// Enumeration order, per-candidate arithmetic, lane-assignment protocol,
// and accumulation order are UNCHANGED -> bit-identical output.
// ---------------------------------------------------------------------------
__global__ __launch_bounds__(256) void select_zgather(
    const float* __restrict__ segMax, const unsigned char* __restrict__ sim4,
    const __hip_bfloat16* __restrict__ QKhi, const __hip_bfloat16* __restrict__ QKlo,
    const float* __restrict__ x,
    __hip_bfloat16* __restrict__ z)
{
  const int lane = threadIdx.x & 63;
  const int n = blockIdx.x * 4 + (threadIdx.x >> 6);

  float2 sm = ((const float2*)(segMax + (size_t)n * 128))[lane];
  float M = fmaxf(sm.x, sm.y);
#pragma unroll
  for (int off = 32; off; off >>= 1) M = fmaxf(M, __shfl_xor(M, off));

  const unsigned long long b0 = __ballot(sm.x > M - 11.0f);
  const unsigned long long b1 = __ballot(sm.y > M - 11.0f);

  // hoist q row (hi+lo reconstruct, 8 dims/lane)
  float qf[8];
  {
    uint4 qh4 = ((const uint4*)(QKhi + (size_t)n * 1024))[lane];
    uint4 ql4 = ((const uint4*)(QKlo + (size_t)n * 1024))[lane];
    float a[8], b[8];
    unpack8(qh4, a); unpack8(ql4, b);
#pragma unroll
    for (int e = 0; e < 8; ++e) qf[e] = a[e] + b[e];
  }

  const unsigned char* srow4 = sim4 + (size_t)n * (NN / 2);
  const int jj = lane >> 4;            // this lane's col-quarter within a seg
  const int shift = (jj & 1) * 4;
  const int boff = (jj >> 1) * 16 + (lane & 15);

  int nk = 0;
  float se_mine = -1e30f;
  int   mm_mine = 0;
#pragma unroll
  for (int half = 0; half < 2; ++half) {
    unsigned long long mask = half ? b1 : b0;
    while (mask) {
      const int b = __ffsll((unsigned long long)mask) - 1;
      mask &= mask - 1;
      const int seg = 2 * b + half;
      const float segv = __shfl(half ? sm.y : sm.x, b);
      const unsigned byte = srow4[seg * 32 + boff];
      const float sa = segv - 0.75f * (float)((byte >> shift) & 15u);
      unsigned long long cm = __ballot(sa > M - 11.0f);

      // ---- depth-1 pipelined candidate loop (cm is wave-uniform) ----
      int c = -1;
      uint4 kh = {}, kl = {};
      if (cm) {
        c = __ffsll(cm) - 1;
        cm &= cm - 1;
        const int m0 = seg * 64 + c;
        kh = ((const uint4*)(QKhi + (size_t)m0 * 1024 + 512))[lane];
        kl = ((const uint4*)(QKlo + (size_t)m0 * 1024 + 512))[lane];
      }
      while (c >= 0) {
        // issue NEXT candidate's loads before consuming current
        int c2 = -1;
        uint4 kh2 = {}, kl2 = {};
        if (cm) {
          c2 = __ffsll(cm) - 1;
          cm &= cm - 1;
          const int m2 = seg * 64 + c2;
          kh2 = ((const uint4*)(QKhi + (size_t)m2 * 1024 + 512))[lane];
          kl2 = ((const uint4*)(QKlo + (size_t)m2 * 1024 + 512))[lane];
        }
        const int m = seg * 64 + c;
        float a[8], bb[8];
        unpack8(kh, a); unpack8(kl, bb);
        float p = 0.f;
#pragma unroll
        for (int e = 0; e < 8; ++e) p += qf[e] * (a[e] + bb[e]);
#pragma unroll
        for (int off = 32; off; off >>= 1) p += __shfl_xor(p, off);
        if (p > M - 10.5f) {
          if (lane == nk) { se_mine = p; mm_mine = m; }
          nk = (nk < 63) ? nk + 1 : nk;
        }
        c = c2; kh = kh2; kl = kl2;
      }
    }
  }

  // exact max + normalizer (selected mass only; tail dropped)
  float Me = (lane < nk) ? se_mine : -1e30f;
#pragma unroll
  for (int off = 32; off; off >>= 1) Me = fmaxf(Me, __shfl_xor(Me, off));
  const float wv = __expf(se_mine - Me);      // valid only for lane < nk
  float Lr = (lane < nk) ? wv : 0.f;
#pragma unroll
  for (int off = 32; off; off >>= 1) Lr += __shfl_xor(Lr, off);

  // ---- depth-1 pipelined gather (indices/weights from registers) ----
  float acc[8] = {};
  float4 ca = {}, cb = {};
  float wcur = 0.f;
  if (nk > 0) {
    const int m0 = __shfl(mm_mine, 0);
    wcur = __shfl(wv, 0);
    const float4* r = (const float4*)(x + (size_t)m0 * CC + 8 * lane);
    ca = r[0]; cb = r[1];
  }
  for (int i = 0; i < nk; ++i) {
    float4 na = {}, nb = {};
    float wnext = 0.f;
    if (i + 1 < nk) {
      const int mn = __shfl(mm_mine, i + 1);
      wnext = __shfl(wv, i + 1);
      const float4* r = (const float4*)(x + (size_t)mn * CC + 8 * lane);
      na = r[0]; nb = r[1];
    }
    acc[0] += wcur * ca.x; acc[1] += wcur * ca.y;
    acc[2] += wcur * ca.z; acc[3] += wcur * ca.w;
    acc[4] += wcur * cb.x; acc[5] += wcur * cb.y;
    acc[6] += wcur * cb.z; acc[7] += wcur * cb.w;
    ca = na; cb = nb; wcur = wnext;
  }
  const float inv = 1.0f / Lr;
  short8 o;
#pragma unroll
  for (int e = 0; e < 8; ++e) {
    __hip_bfloat16 h = __float2bfloat16(acc[e] * inv);
    o[e] = *(short*)&h;
  }
  *(short8*)(z + (size_t)n * CC + 8 * lane) = o;
}

// ---------------------------------------------------------------------------
// gemm_zwk — R18 (frozen): flat 64-virtual-tile loop, triple-buffered 48KB
// LDS, vmcnt(4)-gated single barrier per vt, XOR swizzle, compiler-scheduled
// interior, per-head relu fold, atomicAdd epilogue.
// ---------------------------------------------------------------------------
__global__ __launch_bounds__(256, 2) void gemm_zwk(
    const __hip_bfloat16* __restrict__ z,
    const __hip_bfloat16* __restrict__ WkT,
    const float* __restrict__ bk,
    float* __restrict__ out)
{
  __shared__ __align__(16) char lds[49152];  // 3 bufs x (z 8KB | B 8KB)
  const int tid  = threadIdx.x;              // 0..255
  const int lane = tid & 63;
  const int wave = tid >> 6;                 // 0..3
  const int bn = blockIdx.x, bm = blockIdx.y, hg = blockIdx.z;
  const int wr = wave >> 1, wc = wave & 1;
  const int fr = lane & 15, fq = lane >> 4;

  // staging: dest chunk bytes d0 = tid*16, d1 = 4096 + tid*16 within an
  // 8KB half-buf (128 rows x 64B); source = dest ^ ((dest>>9)&1)<<5.
  int s0 = tid * 16;         s0 ^= ((s0 >> 9) & 1) << 5;
  int s1 = 4096 + tid * 16;  s1 ^= ((s1 >> 9) & 1) << 5;
  const int r0 = s0 >> 6, c0 = (s0 & 63) >> 1;   // row, K-elem
  const int r1 = s1 >> 6, c1 = (s1 & 63) >> 1;

  // fragment read bases (swizzled); row = {wr|wc}*64 + i*16 + fr -> bit3 = fr bit3
  const int fl = ((fr >> 3) & 1) << 5;
  const int baseA = (((wr * 64 + fr) * 64) + fq * 16) ^ fl;
  const int baseB = (((wc * 64 + fr) * 64) + fq * 16) ^ fl;

  const __hip_bfloat16* zb = z + (size_t)(bm * 128) * CC;

  // vt -> head = hg*4 + (vt>>4), kt = (vt&15)*32
#define STAGE_VT(vt, buf) do {                                               \
    const int h_ = hg * 4 + ((vt) >> 4);                                     \
    const int k_ = ((vt) & 15) * 32;                                         \
    const __hip_bfloat16* Bp_ = WkT + (size_t)(h_ * 512 + bn * 128) * CC;    \
    gload_lds16(zb  + (size_t)r0 * CC + k_ + c0, lds + (buf) * 16384 + tid * 16);        \
    gload_lds16(zb  + (size_t)r1 * CC + k_ + c1, lds + (buf) * 16384 + 4096 + tid * 16); \
    gload_lds16(Bp_ + (size_t)r0 * CC + k_ + c0, lds + (buf) * 16384 + 8192 + tid * 16); \
    gload_lds16(Bp_ + (size_t)r1 * CC + k_ + c1, lds + (buf) * 16384 + 12288 + tid * 16);\
  } while (0)

  f32x4 oacc[4][4] = {};

  // prologue: vt 0 -> buf0, vt 1 -> buf1
  STAGE_VT(0, 0);
  STAGE_VT(1, 1);

#pragma unroll
  for (int hh = 0; hh < 4; ++hh) {
    f32x4 acc[4][4] = {};
#pragma unroll
    for (int k2 = 0; k2 < 16; ++k2) {
      const int vt = hh * 16 + k2;
      const int buf = vt % 3;
      const char* Abuf = lds + buf * 16384;
      const char* Bbuf = lds + buf * 16384 + 8192;

      // gate tile vt for all waves
      if (vt == 63) asm volatile("s_waitcnt vmcnt(0)" ::: "memory");
      else          asm volatile("s_waitcnt vmcnt(4)" ::: "memory");
      __builtin_amdgcn_s_barrier();
      __builtin_amdgcn_sched_barrier(0);

      short8 af[4], bf[4];
#pragma unroll
      for (int i = 0; i < 4; ++i) {
        af[i] = *(const short8*)(Abuf + baseA + i * 1024);
        bf[i] = *(const short8*)(Bbuf + baseB + i * 1024);
      }
      if (vt < 62) STAGE_VT(vt + 2, (vt + 2) % 3);

#pragma unroll
      for (int i = 0; i < 4; ++i)
#pragma unroll
        for (int j = 0; j < 4; ++j)
          acc[i][j] = mfma16(af[i], bf[j], acc[i][j]);
    }

    // per-head relu fold
    const int head = hg * 4 + hh;
#pragma unroll
    for (int j = 0; j < 4; ++j) {
      const int d = bn * 128 + wc * 64 + j * 16 + fr;
      const float bias = bk[head * CC + d];
#pragma unroll
      for (int i = 0; i < 4; ++i)
#pragma unroll
        for (int t = 0; t < 4; ++t)
          oacc[i][j][t] += fmaxf(acc[i][j][t] + bias, 0.f);
    }
  }
#undef STAGE_VT

#pragma unroll
  for (int i = 0; i < 4; ++i)
#pragma unroll
    for (int j = 0; j < 4; ++j) {
      const int rbase = bm * 128 + wr * 64 + i * 16 + fq * 4;
      const int d     = bn * 128 + wc * 64 + j * 16 + fr;
#pragma unroll
      for (int t = 0; t < 4; ++t)
        atomicAdd(out + (size_t)(rbase + t) * CC + d, 0.125f * oacc[i][j][t]);
    }
}

// ---------------------------------------------------------------------------
// Merged prep (one launch, block-aligned ranges):
//   [0, 4194304)          x -> bf16 hi+lo split
//   [4194304, 4718592)    WT[j][c] = (j<512?Wth:Wph)[c][j&511], hi+lo
//   [4718592, 6815744)    WkT[j][c] = W_k[j>>9][c][j&511], bf16
//   [6815744, 6816768)    biasqk
//   [6816768, 7865344)    out zero-init (float4 per thread; atomics target)
// ---------------------------------------------------------------------------
__global__ void prep_all(const float* __restrict__ x,
                         const float* __restrict__ Wth, const float* __restrict__ Wph,
                         const float* __restrict__ bt, const float* __restrict__ bp,
                         const float* __restrict__ Wk,
                         __hip_bfloat16* __restrict__ xhi, __hip_bfloat16* __restrict__ xlo,
                         __hip_bfloat16* __restrict__ wthi, __hip_bfloat16* __restrict__ wtlo,
                         __hip_bfloat16* __restrict__ wkt, float* __restrict__ biasqk,
                         float* __restrict__ outz) {
  int idx = blockIdx.x * 256 + threadIdx.x;
  if (idx < 4194304) {
    float v = x[idx];
    __hip_bfloat16 h = __float2bfloat16(v);
    xhi[idx] = h;
    xlo[idx] = __float2bfloat16(v - __bfloat162float(h));
  } else if (idx < 4718592) {
    int i = idx - 4194304;
    int j = i >> 9, c = i & 511;
    const float* W = (j < 512) ? Wth : Wph;
    float v = W[(size_t)c * 512 + (j & 511)];
    __hip_bfloat16 h = __float2bfloat16(v);
    wthi[i] = h;
    wtlo[i] = __float2bfloat16(v - __bfloat162float(h));
  } else if (idx < 6815744) {
    int i = idx - 4718592;
    int j = i >> 9, c = i & 511;
    float v = Wk[(size_t)(j >> 9) * 262144 + (size_t)c * 512 + (j & 511)];
    wkt[i] = __float2bfloat16(v);
  } else if (idx < 6816768) {
    int i = idx - 6815744;
    biasqk[i] = (i < 512) ? bt[i] : bp[i - 512];
  } else if (idx < 7865344) {
    int i = idx - 6816768;
    ((float4*)outz)[i] = make_float4(0.f, 0.f, 0.f, 0.f);
  }
}

extern "C" void kernel_launch(void* const* d_in, const int* in_sizes, int n_in,
                              void* d_out, int out_size, void* d_ws, size_t ws_size,
                              hipStream_t stream) {
  const float* x  = (const float*)d_in[0];
  const float* Wt = (const float*)d_in[1];
  const float* bt = (const float*)d_in[2];
  const float* Wp = (const float*)d_in[3];
  const float* bp = (const float*)d_in[4];
  const float* Wk = (const float*)d_in[5];
  const float* bk = (const float*)d_in[6];
  float* out = (float*)d_out;

  // ---- workspace layout, peak ~100 MiB ----
  const size_t MB = 1024 * 1024;
  char* w = (char*)d_ws;
  __hip_bfloat16* xhi  = (__hip_bfloat16*)(w + 0 * MB);    // 8 MiB
  __hip_bfloat16* xlo  = (__hip_bfloat16*)(w + 8 * MB);    // 8 MiB
  __hip_bfloat16* WThi = (__hip_bfloat16*)(w + 16 * MB);   // 1 MiB
  __hip_bfloat16* WTlo = (__hip_bfloat16*)(w + 17 * MB);   // 1 MiB
  float*          biasqk = (float*)(w + 18 * MB);          // 4 KiB
  __hip_bfloat16* WkT  = (__hip_bfloat16*)(w + 20 * MB);   // 4 MiB
  __hip_bfloat16* QKhi = (__hip_bfloat16*)(w + 24 * MB);   // 16 MiB
  __hip_bfloat16* QKlo = (__hip_bfloat16*)(w + 40 * MB);   // 16 MiB
  __hip_bfloat16* z    = (__hip_bfloat16*)(w + 56 * MB);   // 8 MiB
  float*          segMax = (float*)(w + 64 * MB);          // 4 MiB
  unsigned char*  sim4   = (unsigned char*)(w + 68 * MB);  // 32 MiB

  // 1. prep + out zero-init (single launch)
  prep_all<<<7865344 / 256, 256, 0, stream>>>(x, Wt, Wp, bt, bp, Wk,
                                              xhi, xlo, WThi, WTlo, WkT, biasqk,
                                              out);

  // 2. [Q|K] projections, split precision, hi+lo outputs (8192 x 1024)
  gemm_qk<<<dim3(1024 / 128, NN / 128), 256, 0, stream>>>(
      xhi, xlo, CC, WThi, WTlo, CC, CC, QKhi, QKlo, 1024, biasqk);

  // 3. Q @ K^T -> segMax + deficit nibbles (256x256, compiler-scheduled)
  gemm_sim<<<dim3(NN / 256, NN / 256), 512, 0, stream>>>(
      QKhi, 1024, QKhi + 512, 1024, CC, segMax, sim4);

  // 4. fused select (pipelined nibble-filtered exact recompute) + z-gather
  select_zgather<<<NN / 4, 256, 0, stream>>>(segMax, sim4, QKhi, QKlo, x, z);

  // 5. out[n][d] += 0.125 * sum_{h in hg} relu(z @ W_k[h] + b_k[h])
  gemm_zwk<<<dim3(CC / 128, NN / 128, 2), 256, 0, stream>>>(z, WkT, bk, out);
}